// Round 5
// baseline (128.505 us; speedup 1.0000x reference)
//
#include <hip/hip_runtime.h>
#include <math.h>

#define FLT_BIG 3.0e38f

// Fused kernel: per-ray min squared distance over M points + last-block-per-batch
// exact sum-of-K-smallest selection (register radix select).
// Grid (N/64, B), block 256 = 8 ray-groups x 32 m-chunks; each thread 8 rays.
// LDS: M float4 (x,y,z,0.5|q|^2) = 64KB -> 2 blocks/CU.
__global__ __launch_bounds__(256, 2) void chamfer_fused_kernel(
    const float* __restrict__ cparam,   // B x 25
    const float* __restrict__ depth,    // B x N
    const float* __restrict__ pc,       // B x M x 3
    float* __restrict__ d0,             // B x N scratch (clamped >= 0)
    unsigned int* __restrict__ cnt,     // B counters, pre-zeroed
    float* __restrict__ out,            // B
    int N, int M, int R, int K)
{
    const int b   = blockIdx.y;
    const int tid = threadIdx.x;

    extern __shared__ float4 s4[];      // M entries

    const float* pcb = pc + (size_t)b * M * 3;
    for (int idx = tid; idx < M; idx += 256) {
        float x = pcb[idx * 3 + 0];
        float y = pcb[idx * 3 + 1];
        float z = pcb[idx * 3 + 2];
        s4[idx] = make_float4(x, y, z, 0.5f * (x * x + y * y + z * z));
    }
    __syncthreads();

    const float* cb = cparam + (size_t)b * 25;
    const float fx = cb[16], sk = cb[17], cx = cb[18];
    const float fy = cb[20], cy = cb[21];

    const int chunk = tid & 31;              // m-chunk 0..31
    const int grp   = tid >> 5;              // ray group 0..7
    const int nbase = blockIdx.x * 64 + grp * 8;

    float px[8], py[8], pz[8], e[8];
    #pragma unroll
    for (int r = 0; r < 8; r++) {
        const int n = nbase + r;
        const int i = n / R;
        const int j = n - i * R;
        const float x_cam = (j + 0.5f) / (float)R;
        const float y_cam = (i + 0.5f) / (float)R;
        const float x_lift = (x_cam - cx + cy * sk / fy - sk * y_cam / fy) / fx;
        const float y_lift = (y_cam - cy) / fy;
        const float dxw = cb[0] * x_lift + cb[1] * y_lift + cb[2];
        const float dyw = cb[4] * x_lift + cb[5] * y_lift + cb[6];
        const float dzw = cb[8] * x_lift + cb[9] * y_lift + cb[10];
        const float inv = 1.0f / sqrtf(dxw * dxw + dyw * dyw + dzw * dzw);
        const float dep = depth[(size_t)b * N + n];
        px[r] = cb[3]  + dep * dxw * inv;
        py[r] = cb[7]  + dep * dyw * inv;
        pz[r] = cb[11] + dep * dzw * inv;
        e[r]  = FLT_BIG;
    }

    const int Mc = M >> 5;                   // points per chunk (128)
    #pragma unroll 4
    for (int m = 0; m < Mc; m++) {
        const float4 q = s4[(m << 5) + chunk];
        #pragma unroll
        for (int r = 0; r < 8; r++) {
            float t = fmaf(-px[r], q.x, q.w);
            t = fmaf(-py[r], q.y, t);
            t = fmaf(-pz[r], q.z, t);
            e[r] = fminf(e[r], t);
        }
    }

    #pragma unroll
    for (int r = 0; r < 8; r++) {
        float v = e[r];
        v = fminf(v, __shfl_xor(v, 1));
        v = fminf(v, __shfl_xor(v, 2));
        v = fminf(v, __shfl_xor(v, 4));
        v = fminf(v, __shfl_xor(v, 8));
        v = fminf(v, __shfl_xor(v, 16));
        e[r] = v;
    }
    if (chunk == 0) {
        #pragma unroll
        for (int r = 0; r < 8; r++) {
            const int n = nbase + r;
            const float pn = px[r] * px[r] + py[r] * py[r] + pz[r] * pz[r];
            // clamp >= 0: true dist^2 is non-negative; float bits uint-monotone
            d0[(size_t)b * N + n] = fmaxf(2.0f * e[r] + pn, 0.0f);
        }
    }

    // ---- last-block-done handoff ----
    __shared__ unsigned int is_last;
    __syncthreads();                         // drains vmcnt: d0 stores left the CU
    if (tid == 0) {
        __threadfence();                     // release: flush this XCD's L2
        unsigned int old = atomicAdd(&cnt[b], 1u);
        is_last = (old == gridDim.x - 1) ? 1u : 0u;
    }
    __syncthreads();
    if (!is_last) return;
    __threadfence();                         // acquire: invalidate stale L1/L2

    // ---- selection: exact sum of K smallest of N=16*256 non-negative floats.
    // 16 keys/thread in registers; 4-bit radix select, 8 rounds, predicated adds.
    const int lane = tid & 63;
    const int wv   = tid >> 6;
    __shared__ unsigned int wcnt[4 * 16];
    __shared__ unsigned int sel[2];
    __shared__ float  fpart[4];
    __shared__ unsigned int cpart[4];

    unsigned int key[16];
    #pragma unroll
    for (int t = 0; t < 16; t++)
        key[t] = __float_as_uint(d0[(size_t)b * N + t * 256 + tid]);

    unsigned int k = (unsigned int)K;
    unsigned int prefix = 0u, mask = 0u;

    #pragma unroll
    for (int shift = 28; shift >= 0; shift -= 4) {
        unsigned int c[16];
        #pragma unroll
        for (int j2 = 0; j2 < 16; j2++) c[j2] = 0u;

        #pragma unroll
        for (int t = 0; t < 16; t++) {
            const unsigned int kk = key[t];
            const bool m2 = (kk & mask) == prefix;
            const unsigned int nib = (kk >> shift) & 15u;
            #pragma unroll
            for (int j2 = 0; j2 < 16; j2++)
                c[j2] += (unsigned int)(m2 && (nib == (unsigned int)j2));
        }

        #pragma unroll
        for (int j2 = 0; j2 < 16; j2++) {
            unsigned int v = c[j2];
            v += __shfl_xor(v, 1);  v += __shfl_xor(v, 2);
            v += __shfl_xor(v, 4);  v += __shfl_xor(v, 8);
            v += __shfl_xor(v, 16); v += __shfl_xor(v, 32);
            c[j2] = v;
        }
        if (lane == 0) {
            #pragma unroll
            for (int j2 = 0; j2 < 16; j2++) wcnt[wv * 16 + j2] = c[j2];
        }
        __syncthreads();

        if (tid < 16) {
            unsigned int tot = wcnt[tid] + wcnt[16 + tid] + wcnt[32 + tid] + wcnt[48 + tid];
            unsigned int cum = tot;
            #pragma unroll
            for (int off = 1; off < 16; off <<= 1) {
                unsigned int u = __shfl_up(cum, off);
                if (tid >= off) cum += u;
            }
            const unsigned int cprev = cum - tot;
            if (cprev < k && k <= cum) { sel[0] = (unsigned int)tid; sel[1] = k - cprev; }
        }
        __syncthreads();

        prefix |= sel[0] << shift;
        k = sel[1];
        mask |= 15u << shift;
    }
    // prefix == float bits of the K-th smallest value T.

    const float tval = __uint_as_float(prefix);
    float sum = 0.0f;
    unsigned int cnt2 = 0u;
    #pragma unroll
    for (int t = 0; t < 16; t++) {
        if (key[t] < prefix) { sum += __uint_as_float(key[t]); cnt2++; }
    }
    #pragma unroll
    for (int off = 32; off > 0; off >>= 1) {
        sum  += __shfl_xor(sum, off);
        cnt2 += __shfl_xor(cnt2, off);
    }
    if (lane == 0) { fpart[wv] = sum; cpart[wv] = cnt2; }
    __syncthreads();
    if (tid == 0) {
        float s = fpart[0] + fpart[1] + fpart[2] + fpart[3];
        unsigned int c2 = cpart[0] + cpart[1] + cpart[2] + cpart[3];
        s += (float)(K - (int)c2) * tval;     // ties / exact-Kth fill
        out[b] = 2.0f * s / (float)K;
    }
}

extern "C" void kernel_launch(void* const* d_in, const int* in_sizes, int n_in,
                              void* d_out, int out_size, void* d_ws, size_t ws_size,
                              hipStream_t stream)
{
    const float* c   = (const float*)d_in[0];
    const float* dep = (const float*)d_in[1];
    const float* pc  = (const float*)d_in[2];
    float* out = (float*)d_out;

    const int B = in_sizes[0] / 25;
    const int N = in_sizes[1] / B;     // 4096 (= 16*256, assumed by selection)
    const int M = in_sizes[2] / (3 * B);
    int R = 1; while (R * R < N) R++;

    float* d0 = (float*)d_ws;                          // B*N floats
    unsigned int* cnt = (unsigned int*)(d0 + (size_t)B * N);  // B counters

    hipMemsetAsync(cnt, 0, (size_t)B * sizeof(unsigned int), stream);

    const int K = ((N < M) ? N : M) / 2;
    dim3 grid(N / 64, B);
    size_t lds = (size_t)M * sizeof(float4);
    hipLaunchKernelGGL(chamfer_fused_kernel, grid, dim3(256), lds, stream,
                       c, dep, pc, d0, cnt, out, N, M, R, K);
}

// Round 6
// 99.868 us; speedup vs baseline: 1.2868x; 1.2868x over previous
//
#include <hip/hip_runtime.h>
#include <math.h>

#define FLT_BIG 3.0e38f
#define HIST_BINS 16384   // float bits >> 18 : sign(0)+exp(8)+mant(5)

// Fused: per-ray min dist^2 over M points + last-block-per-batch histogram select.
// Grid (N/64, B), block 256 = 8 ray-groups x 32 m-chunks; 8 rays/thread.
// LDS: M float4 (x,y,z,0.5|q|^2) = 64KB; reused as uint hist[16384] in the tail.
__global__ __launch_bounds__(256, 2) void chamfer_fused_kernel(
    const float* __restrict__ cparam,   // B x 25
    const float* __restrict__ depth,    // B x N
    const float* __restrict__ pc,       // B x M x 3
    float* __restrict__ d0,             // B x N scratch (clamped >= 0)
    unsigned int* __restrict__ cnt,     // B counters, pre-zeroed
    float* __restrict__ out,            // B
    int N, int M, int R, int K)
{
    const int b   = blockIdx.y;
    const int tid = threadIdx.x;

    extern __shared__ float4 s4[];      // M entries (>= HIST_BINS uints)

    const float* pcb = pc + (size_t)b * M * 3;
    for (int idx = tid; idx < M; idx += 256) {
        float x = pcb[idx * 3 + 0];
        float y = pcb[idx * 3 + 1];
        float z = pcb[idx * 3 + 2];
        s4[idx] = make_float4(x, y, z, 0.5f * (x * x + y * y + z * z));
    }
    __syncthreads();

    const float* cb = cparam + (size_t)b * 25;
    const float fx = cb[16], sk = cb[17], cx = cb[18];
    const float fy = cb[20], cy = cb[21];

    const int chunk = tid & 31;              // m-chunk 0..31
    const int grp   = tid >> 5;              // ray group 0..7
    const int nbase = blockIdx.x * 64 + grp * 8;

    // All 8 rays share a row: nbase % 8 == 0 and 8 | R.
    const int i0 = nbase / R;
    const int j0 = nbase - i0 * R;
    const float y_cam = (i0 + 0.5f) / (float)R;
    const float y_lift = (y_cam - cy) / fy;
    const float base_x = (-cx + cy * sk / fy - sk * y_cam / fy);

    float px[8], py[8], pz[8], e[8];
    #pragma unroll
    for (int r = 0; r < 8; r++) {
        const float x_cam = (j0 + r + 0.5f) / (float)R;
        const float x_lift = (x_cam + base_x) / fx;
        const float dxw = cb[0] * x_lift + cb[1] * y_lift + cb[2];
        const float dyw = cb[4] * x_lift + cb[5] * y_lift + cb[6];
        const float dzw = cb[8] * x_lift + cb[9] * y_lift + cb[10];
        const float inv = 1.0f / sqrtf(dxw * dxw + dyw * dyw + dzw * dzw);
        const float dep = depth[(size_t)b * N + nbase + r];
        px[r] = cb[3]  + dep * dxw * inv;
        py[r] = cb[7]  + dep * dyw * inv;
        pz[r] = cb[11] + dep * dzw * inv;
        e[r]  = FLT_BIG;
    }

    const int Mc = M >> 5;                   // points per chunk (128)
    #pragma unroll 4
    for (int m = 0; m < Mc; m++) {
        const float4 q = s4[(m << 5) + chunk];
        #pragma unroll
        for (int r = 0; r < 8; r++) {
            float t = fmaf(-px[r], q.x, q.w);
            t = fmaf(-py[r], q.y, t);
            t = fmaf(-pz[r], q.z, t);
            e[r] = fminf(e[r], t);
        }
    }

    #pragma unroll
    for (int r = 0; r < 8; r++) {
        float v = e[r];
        v = fminf(v, __shfl_xor(v, 1));
        v = fminf(v, __shfl_xor(v, 2));
        v = fminf(v, __shfl_xor(v, 4));
        v = fminf(v, __shfl_xor(v, 8));
        v = fminf(v, __shfl_xor(v, 16));
        e[r] = v;
    }
    if (chunk == 0) {
        #pragma unroll
        for (int r = 0; r < 8; r++) {
            const float pn = px[r] * px[r] + py[r] * py[r] + pz[r] * pz[r];
            // clamp >= 0: float bits become uint-monotone for the histogram
            d0[(size_t)b * N + nbase + r] = fmaxf(2.0f * e[r] + pn, 0.0f);
        }
    }

    // ---- last-block-done handoff ----
    __shared__ unsigned int is_last;
    __syncthreads();                         // drains vmcnt: d0 stores left the CU
    if (tid == 0) {
        __threadfence();                     // release
        unsigned int old = atomicAdd(&cnt[b], 1u);
        is_last = (old == gridDim.x - 1) ? 1u : 0u;
    }
    __syncthreads();
    if (!is_last) return;
    __threadfence();                         // acquire

    // ---- tail: histogram select (no shuffles; one block, 8 per device) ----
    unsigned int* hist = (unsigned int*)s4;  // reuse 64KB LDS
    __shared__ unsigned int spart[256];
    __shared__ unsigned int s_selbin, s_krem;
    __shared__ unsigned int subcnt[32];
    __shared__ float        subsum[32];
    __shared__ float        s_below;

    for (int t2 = tid; t2 < HIST_BINS; t2 += 256) hist[t2] = 0u;
    if (tid < 32) { subcnt[tid] = 0u; subsum[tid] = 0.0f; }
    if (tid == 0) s_below = 0.0f;
    __syncthreads();

    unsigned int key[16];
    #pragma unroll
    for (int t2 = 0; t2 < 16; t2++)
        key[t2] = __float_as_uint(d0[(size_t)b * N + t2 * 256 + tid]);
    #pragma unroll
    for (int t2 = 0; t2 < 16; t2++)
        atomicAdd(&hist[key[t2] >> 18], 1u);
    __syncthreads();

    // partial counts: thread t owns bins [64t, 64t+64)
    unsigned int psum = 0u;
    #pragma unroll 8
    for (int i2 = 0; i2 < 64; i2++) psum += hist[tid * 64 + i2];
    spart[tid] = psum;
    __syncthreads();

    unsigned int cbef = 0u;
    for (int i2 = 0; i2 < tid; i2++) cbef += spart[i2];   // broadcast reads
    if (cbef < (unsigned int)K && (unsigned int)K <= cbef + psum) {
        unsigned int k2 = (unsigned int)K - cbef;
        unsigned int sel = 0u;
        for (int i2 = 0; i2 < 64; i2++) {
            unsigned int h = hist[tid * 64 + i2];
            if (k2 <= h) { sel = tid * 64 + i2; break; }
            k2 -= h;
        }
        s_selbin = sel;
        s_krem   = k2;
    }
    __syncthreads();

    const unsigned int selbin = s_selbin;
    float sumb = 0.0f;
    #pragma unroll
    for (int t2 = 0; t2 < 16; t2++) {
        const unsigned int bin = key[t2] >> 18;
        const float v = __uint_as_float(key[t2]);
        if (bin < selbin) sumb += v;
        if (bin == selbin) {
            const unsigned int sub = (key[t2] >> 13) & 31u;
            atomicAdd(&subcnt[sub], 1u);
            atomicAdd(&subsum[sub], v);
        }
    }
    atomicAdd(&s_below, sumb);
    __syncthreads();

    if (tid == 0) {
        unsigned int k2 = s_krem;
        float s = s_below;
        for (int i2 = 0; i2 < 32; i2++) {
            unsigned int h = subcnt[i2];
            if (k2 <= h) {
                // fill remaining k2 with the sub-bin mean (width T/1024)
                s += (h ? (subsum[i2] * ((float)k2 / (float)h)) : 0.0f);
                break;
            }
            s += subsum[i2];
            k2 -= h;
        }
        out[b] = 2.0f * s / (float)K;
    }
}

extern "C" void kernel_launch(void* const* d_in, const int* in_sizes, int n_in,
                              void* d_out, int out_size, void* d_ws, size_t ws_size,
                              hipStream_t stream)
{
    const float* c   = (const float*)d_in[0];
    const float* dep = (const float*)d_in[1];
    const float* pc  = (const float*)d_in[2];
    float* out = (float*)d_out;

    const int B = in_sizes[0] / 25;
    const int N = in_sizes[1] / B;     // 4096 (= 16*256, assumed by selection)
    const int M = in_sizes[2] / (3 * B);
    int R = 1; while (R * R < N) R++;

    float* d0 = (float*)d_ws;                                 // B*N floats
    unsigned int* cnt = (unsigned int*)(d0 + (size_t)B * N);  // B counters

    hipMemsetAsync(cnt, 0, (size_t)B * sizeof(unsigned int), stream);

    const int K = ((N < M) ? N : M) / 2;
    dim3 grid(N / 64, B);
    size_t lds = (size_t)M * sizeof(float4);                  // 64KB >= hist
    if (lds < HIST_BINS * sizeof(unsigned int)) lds = HIST_BINS * sizeof(unsigned int);
    hipLaunchKernelGGL(chamfer_fused_kernel, grid, dim3(256), lds, stream,
                       c, dep, pc, d0, cnt, out, N, M, R, K);
}

// Round 7
// 96.135 us; speedup vs baseline: 1.3367x; 1.0388x over previous
//
#include <hip/hip_runtime.h>
#include <math.h>

#define FLT_BIG 3.0e38f
#define HIST_BINS 16384   // float bits >> 18 : sign(0)+exp(8)+mant(5)
#define CNT_STRIDE 64     // spread batch counters 256B apart (separate cache lines)

// Fused: per-ray min dist^2 over M points + last-block-per-batch histogram select.
// Grid (N/64, B), block 256 = 8 ray-groups x 32 m-chunks; 8 rays/thread.
// LDS: M float4 (x,y,z,0.5|q|^2) = 64KB; reused as uint hist[16384] in the tail.
__global__ __launch_bounds__(256, 2) void chamfer_fused_kernel(
    const float* __restrict__ cparam,   // B x 25
    const float* __restrict__ depth,    // B x N
    const float* __restrict__ pc,       // B x M x 3
    float* __restrict__ d0,             // B x N scratch (clamped >= 0)
    unsigned int* __restrict__ cnt,     // B*CNT_STRIDE, pre-zeroed
    float* __restrict__ out,            // B
    int N, int M, int R, int K)
{
    const int b   = blockIdx.y;
    const int tid = threadIdx.x;

    extern __shared__ float4 s4[];      // M entries (>= HIST_BINS uints)

    const float* pcb = pc + (size_t)b * M * 3;
    for (int idx = tid; idx < M; idx += 256) {
        float x = pcb[idx * 3 + 0];
        float y = pcb[idx * 3 + 1];
        float z = pcb[idx * 3 + 2];
        s4[idx] = make_float4(x, y, z, 0.5f * (x * x + y * y + z * z));
    }
    __syncthreads();

    const float* cb = cparam + (size_t)b * 25;
    const float fx = cb[16], sk = cb[17], cx = cb[18];
    const float fy = cb[20], cy = cb[21];

    const int chunk = tid & 31;              // m-chunk 0..31
    const int grp   = tid >> 5;              // ray group 0..7
    const int nbase = blockIdx.x * 64 + grp * 8;

    // All 8 rays share a row: nbase % 8 == 0 and 8 | R.
    const int i0 = nbase / R;
    const int j0 = nbase - i0 * R;
    const float y_cam = (i0 + 0.5f) / (float)R;
    const float y_lift = (y_cam - cy) / fy;
    const float base_x = (-cx + cy * sk / fy - sk * y_cam / fy);

    float px[8], py[8], pz[8], e[8];
    #pragma unroll
    for (int r = 0; r < 8; r++) {
        const float x_cam = (j0 + r + 0.5f) / (float)R;
        const float x_lift = (x_cam + base_x) / fx;
        const float dxw = cb[0] * x_lift + cb[1] * y_lift + cb[2];
        const float dyw = cb[4] * x_lift + cb[5] * y_lift + cb[6];
        const float dzw = cb[8] * x_lift + cb[9] * y_lift + cb[10];
        const float inv = 1.0f / sqrtf(dxw * dxw + dyw * dyw + dzw * dzw);
        const float dep = depth[(size_t)b * N + nbase + r];
        px[r] = cb[3]  + dep * dxw * inv;
        py[r] = cb[7]  + dep * dyw * inv;
        pz[r] = cb[11] + dep * dzw * inv;
        e[r]  = FLT_BIG;
    }

    // Main loop: 8 hoisted ds_read_b128 in flight, then 256 independent VALU ops.
    const int Mc = M >> 5;                   // points per chunk (128), 8 | Mc
    for (int m = 0; m < Mc; m += 8) {
        float4 q[8];
        #pragma unroll
        for (int mm = 0; mm < 8; mm++)
            q[mm] = s4[((m + mm) << 5) + chunk];
        #pragma unroll
        for (int mm = 0; mm < 8; mm++) {
            #pragma unroll
            for (int r = 0; r < 8; r++) {
                float t = fmaf(-px[r], q[mm].x, q[mm].w);
                t = fmaf(-py[r], q[mm].y, t);
                t = fmaf(-pz[r], q[mm].z, t);
                e[r] = fminf(e[r], t);
            }
        }
    }

    #pragma unroll
    for (int r = 0; r < 8; r++) {
        float v = e[r];
        v = fminf(v, __shfl_xor(v, 1));
        v = fminf(v, __shfl_xor(v, 2));
        v = fminf(v, __shfl_xor(v, 4));
        v = fminf(v, __shfl_xor(v, 8));
        v = fminf(v, __shfl_xor(v, 16));
        e[r] = v;
    }
    if (chunk == 0) {
        #pragma unroll
        for (int r = 0; r < 8; r++) {
            const float pn = px[r] * px[r] + py[r] * py[r] + pz[r] * pz[r];
            // clamp >= 0: float bits become uint-monotone for the histogram
            d0[(size_t)b * N + nbase + r] = fmaxf(2.0f * e[r] + pn, 0.0f);
        }
    }

    // ---- last-block-done handoff (counters on separate cache lines) ----
    __shared__ unsigned int is_last;
    __syncthreads();                         // drains vmcnt: d0 stores left the CU
    if (tid == 0) {
        __threadfence();                     // release
        unsigned int old = atomicAdd(&cnt[b * CNT_STRIDE], 1u);
        is_last = (old == gridDim.x - 1) ? 1u : 0u;
    }
    __syncthreads();
    if (!is_last) return;
    __threadfence();                         // acquire

    // ---- tail: histogram select (one block per batch) ----
    unsigned int* hist = (unsigned int*)s4;  // reuse 64KB LDS
    __shared__ unsigned int spart[256];
    __shared__ unsigned int s_selbin, s_krem;
    __shared__ unsigned int subcnt[32];
    __shared__ float        subsum[32];
    __shared__ float        s_below;

    for (int t2 = tid; t2 < HIST_BINS; t2 += 256) hist[t2] = 0u;
    if (tid < 32) { subcnt[tid] = 0u; subsum[tid] = 0.0f; }
    if (tid == 0) s_below = 0.0f;
    __syncthreads();

    unsigned int key[16];
    #pragma unroll
    for (int t2 = 0; t2 < 16; t2++)
        key[t2] = __float_as_uint(d0[(size_t)b * N + t2 * 256 + tid]);
    #pragma unroll
    for (int t2 = 0; t2 < 16; t2++)
        atomicAdd(&hist[key[t2] >> 18], 1u);
    __syncthreads();

    // partial counts: thread t owns bins [64t, 64t+64); XOR-rotate to spread banks
    unsigned int psum = 0u;
    #pragma unroll 8
    for (int i2 = 0; i2 < 64; i2++)
        psum += hist[(tid << 6) + ((i2 + tid) & 63)];
    spart[tid] = psum;
    __syncthreads();

    unsigned int cbef = 0u;
    for (int i2 = 0; i2 < tid; i2++) cbef += spart[i2];   // broadcast reads
    if (cbef < (unsigned int)K && (unsigned int)K <= cbef + psum) {
        unsigned int k2 = (unsigned int)K - cbef;
        unsigned int sel = 0u;
        for (int i2 = 0; i2 < 64; i2++) {
            unsigned int h = hist[(tid << 6) + i2];
            if (k2 <= h) { sel = (tid << 6) + i2; break; }
            k2 -= h;
        }
        s_selbin = sel;
        s_krem   = k2;
    }
    __syncthreads();

    const unsigned int selbin = s_selbin;
    float sumb = 0.0f;
    #pragma unroll
    for (int t2 = 0; t2 < 16; t2++) {
        const unsigned int bin = key[t2] >> 18;
        const float v = __uint_as_float(key[t2]);
        if (bin < selbin) sumb += v;
        if (bin == selbin) {
            const unsigned int sub = (key[t2] >> 13) & 31u;
            atomicAdd(&subcnt[sub], 1u);
            atomicAdd(&subsum[sub], v);
        }
    }
    atomicAdd(&s_below, sumb);
    __syncthreads();

    if (tid == 0) {
        unsigned int k2 = s_krem;
        float s = s_below;
        for (int i2 = 0; i2 < 32; i2++) {
            unsigned int h = subcnt[i2];
            if (k2 <= h) {
                s += (h ? (subsum[i2] * ((float)k2 / (float)h)) : 0.0f);
                break;
            }
            s += subsum[i2];
            k2 -= h;
        }
        out[b] = 2.0f * s / (float)K;
    }
}

extern "C" void kernel_launch(void* const* d_in, const int* in_sizes, int n_in,
                              void* d_out, int out_size, void* d_ws, size_t ws_size,
                              hipStream_t stream)
{
    const float* c   = (const float*)d_in[0];
    const float* dep = (const float*)d_in[1];
    const float* pc  = (const float*)d_in[2];
    float* out = (float*)d_out;

    const int B = in_sizes[0] / 25;
    const int N = in_sizes[1] / B;     // 4096 (= 16*256, assumed by selection)
    const int M = in_sizes[2] / (3 * B);
    int R = 1; while (R * R < N) R++;

    float* d0 = (float*)d_ws;                                 // B*N floats
    unsigned int* cnt = (unsigned int*)(d0 + (size_t)B * N);  // B*CNT_STRIDE u32

    hipMemsetAsync(cnt, 0, (size_t)B * CNT_STRIDE * sizeof(unsigned int), stream);

    const int K = ((N < M) ? N : M) / 2;
    dim3 grid(N / 64, B);
    size_t lds = (size_t)M * sizeof(float4);                  // 64KB >= hist
    if (lds < HIST_BINS * sizeof(unsigned int)) lds = HIST_BINS * sizeof(unsigned int);
    hipLaunchKernelGGL(chamfer_fused_kernel, grid, dim3(256), lds, stream,
                       c, dep, pc, d0, cnt, out, N, M, R, K);
}

// Round 8
// 88.113 us; speedup vs baseline: 1.4584x; 1.0910x over previous
//
#include <hip/hip_runtime.h>
#include <math.h>

#define FLT_BIG 3.0e38f
#define HIST_BINS 16384   // float bits >> 18 : sign(0)+exp(8)+mant(5)

// Kernel A: per-ray min dist^2 over M points. Pure compute, no handoff.
// Grid (N/64, B), block 256 = 8 ray-groups x 32 m-chunks; 8 rays/thread.
// LDS: M float4 (x,y,z,0.5|q|^2) = 64KB -> 2 blocks/CU.
__global__ __launch_bounds__(256, 2) void chamfer_min_kernel(
    const float* __restrict__ cparam,   // B x 25
    const float* __restrict__ depth,    // B x N
    const float* __restrict__ pc,       // B x M x 3
    float* __restrict__ d0,             // B x N (clamped >= 0)
    int N, int M, int R)
{
    const int b   = blockIdx.y;
    const int tid = threadIdx.x;

    extern __shared__ float4 s4[];      // M entries

    const float* pcb = pc + (size_t)b * M * 3;
    for (int idx = tid; idx < M; idx += 256) {
        float x = pcb[idx * 3 + 0];
        float y = pcb[idx * 3 + 1];
        float z = pcb[idx * 3 + 2];
        s4[idx] = make_float4(x, y, z, 0.5f * (x * x + y * y + z * z));
    }
    __syncthreads();

    const float* cb = cparam + (size_t)b * 25;
    const float fx = cb[16], sk = cb[17], cx = cb[18];
    const float fy = cb[20], cy = cb[21];

    const int chunk = tid & 31;              // m-chunk 0..31
    const int grp   = tid >> 5;              // ray group 0..7
    const int nbase = blockIdx.x * 64 + grp * 8;

    // All 8 rays share a row: nbase % 8 == 0 and 8 | R.
    const int i0 = nbase / R;
    const int j0 = nbase - i0 * R;
    const float y_cam = (i0 + 0.5f) / (float)R;
    const float y_lift = (y_cam - cy) / fy;
    const float base_x = (-cx + cy * sk / fy - sk * y_cam / fy);

    float px[8], py[8], pz[8], e[8];
    #pragma unroll
    for (int r = 0; r < 8; r++) {
        const float x_cam = (j0 + r + 0.5f) / (float)R;
        const float x_lift = (x_cam + base_x) / fx;
        const float dxw = cb[0] * x_lift + cb[1] * y_lift + cb[2];
        const float dyw = cb[4] * x_lift + cb[5] * y_lift + cb[6];
        const float dzw = cb[8] * x_lift + cb[9] * y_lift + cb[10];
        const float inv = 1.0f / sqrtf(dxw * dxw + dyw * dyw + dzw * dzw);
        const float dep = depth[(size_t)b * N + nbase + r];
        px[r] = cb[3]  + dep * dxw * inv;
        py[r] = cb[7]  + dep * dyw * inv;
        pz[r] = cb[11] + dep * dzw * inv;
        e[r]  = FLT_BIG;
    }

    // Main loop: 8 hoisted ds_read_b128 in flight, then 256 independent VALU ops.
    const int Mc = M >> 5;                   // points per chunk (128), 8 | Mc
    for (int m = 0; m < Mc; m += 8) {
        float4 q[8];
        #pragma unroll
        for (int mm = 0; mm < 8; mm++)
            q[mm] = s4[((m + mm) << 5) + chunk];
        #pragma unroll
        for (int mm = 0; mm < 8; mm++) {
            #pragma unroll
            for (int r = 0; r < 8; r++) {
                float t = fmaf(-px[r], q[mm].x, q[mm].w);
                t = fmaf(-py[r], q[mm].y, t);
                t = fmaf(-pz[r], q[mm].z, t);
                e[r] = fminf(e[r], t);
            }
        }
    }

    #pragma unroll
    for (int r = 0; r < 8; r++) {
        float v = e[r];
        v = fminf(v, __shfl_xor(v, 1));
        v = fminf(v, __shfl_xor(v, 2));
        v = fminf(v, __shfl_xor(v, 4));
        v = fminf(v, __shfl_xor(v, 8));
        v = fminf(v, __shfl_xor(v, 16));
        e[r] = v;
    }
    if (chunk == 0) {
        #pragma unroll
        for (int r = 0; r < 8; r++) {
            const float pn = px[r] * px[r] + py[r] * py[r] + pz[r] * pz[r];
            // clamp >= 0: float bits become uint-monotone for kernel B
            d0[(size_t)b * N + nbase + r] = fmaxf(2.0f * e[r] + pn, 0.0f);
        }
    }
}

// Kernel B: per-batch histogram select. One 256-thread block per batch.
// Exact sum of values strictly below the straddling sub-bin + mean fill there.
__global__ __launch_bounds__(256, 1) void select_mean_kernel(
    const float* __restrict__ d0,
    float* __restrict__ out,
    int N, int K)
{
    const int b   = blockIdx.x;
    const int tid = threadIdx.x;

    extern __shared__ unsigned int hist[];   // HIST_BINS
    __shared__ unsigned int spart[256];
    __shared__ unsigned int s_selbin, s_krem;
    __shared__ unsigned int subcnt[32];
    __shared__ float        subsum[32];
    __shared__ float        s_below;

    for (int t2 = tid; t2 < HIST_BINS; t2 += 256) hist[t2] = 0u;
    if (tid < 32) { subcnt[tid] = 0u; subsum[tid] = 0.0f; }
    if (tid == 0) s_below = 0.0f;
    __syncthreads();

    unsigned int key[16];
    #pragma unroll
    for (int t2 = 0; t2 < 16; t2++)
        key[t2] = __float_as_uint(d0[(size_t)b * N + t2 * 256 + tid]);
    #pragma unroll
    for (int t2 = 0; t2 < 16; t2++)
        atomicAdd(&hist[key[t2] >> 18], 1u);
    __syncthreads();

    // partial counts: thread t owns bins [64t, 64t+64); rotate to spread banks
    unsigned int psum = 0u;
    #pragma unroll 8
    for (int i2 = 0; i2 < 64; i2++)
        psum += hist[(tid << 6) + ((i2 + tid) & 63)];
    spart[tid] = psum;
    __syncthreads();

    unsigned int cbef = 0u;
    for (int i2 = 0; i2 < tid; i2++) cbef += spart[i2];   // broadcast reads
    if (cbef < (unsigned int)K && (unsigned int)K <= cbef + psum) {
        unsigned int k2 = (unsigned int)K - cbef;
        unsigned int sel = 0u;
        for (int i2 = 0; i2 < 64; i2++) {
            unsigned int h = hist[(tid << 6) + i2];
            if (k2 <= h) { sel = (tid << 6) + i2; break; }
            k2 -= h;
        }
        s_selbin = sel;
        s_krem   = k2;
    }
    __syncthreads();

    const unsigned int selbin = s_selbin;
    float sumb = 0.0f;
    #pragma unroll
    for (int t2 = 0; t2 < 16; t2++) {
        const unsigned int bin = key[t2] >> 18;
        const float v = __uint_as_float(key[t2]);
        if (bin < selbin) sumb += v;
        if (bin == selbin) {
            const unsigned int sub = (key[t2] >> 13) & 31u;
            atomicAdd(&subcnt[sub], 1u);
            atomicAdd(&subsum[sub], v);
        }
    }
    atomicAdd(&s_below, sumb);
    __syncthreads();

    if (tid == 0) {
        unsigned int k2 = s_krem;
        float s = s_below;
        for (int i2 = 0; i2 < 32; i2++) {
            unsigned int h = subcnt[i2];
            if (k2 <= h) {
                // fill remaining k2 with sub-bin mean (rel width 2^-10)
                s += (h ? (subsum[i2] * ((float)k2 / (float)h)) : 0.0f);
                break;
            }
            s += subsum[i2];
            k2 -= h;
        }
        out[b] = 2.0f * s / (float)K;
    }
}

extern "C" void kernel_launch(void* const* d_in, const int* in_sizes, int n_in,
                              void* d_out, int out_size, void* d_ws, size_t ws_size,
                              hipStream_t stream)
{
    const float* c   = (const float*)d_in[0];
    const float* dep = (const float*)d_in[1];
    const float* pc  = (const float*)d_in[2];
    float* out = (float*)d_out;

    const int B = in_sizes[0] / 25;
    const int N = in_sizes[1] / B;     // 4096 (= 16*256, assumed by kernel B)
    const int M = in_sizes[2] / (3 * B);
    int R = 1; while (R * R < N) R++;

    float* d0 = (float*)d_ws;          // B*N floats of scratch

    dim3 gridA(N / 64, B);
    size_t ldsA = (size_t)M * sizeof(float4);
    hipLaunchKernelGGL(chamfer_min_kernel, gridA, dim3(256), ldsA, stream,
                       c, dep, pc, d0, N, M, R);

    const int K = ((N < M) ? N : M) / 2;
    size_t ldsB = (size_t)HIST_BINS * sizeof(unsigned int);
    hipLaunchKernelGGL(select_mean_kernel, dim3(B), dim3(256), ldsB, stream,
                       d0, out, N, K);
}

// Round 9
// 81.850 us; speedup vs baseline: 1.5700x; 1.0765x over previous
//
#include <hip/hip_runtime.h>
#include <math.h>

#define FLT_BIG 3.0e38f
#define HIST_BINS 16384   // float bits >> 18 : sign(0)+exp(8)+mant(5)

typedef short short8 __attribute__((ext_vector_type(8)));
typedef float floatx4 __attribute__((ext_vector_type(4)));

union U4S8 { uint4 u; short8 s; };

// round-to-nearest-even f32 -> bf16 bits
static __device__ __forceinline__ unsigned int f2bf(float f) {
    unsigned int u = __float_as_uint(f);
    return (u + 0x7FFFu + ((u >> 16) & 1u)) >> 16;
}
static __device__ __forceinline__ float bf2f(unsigned int b) {
    return __uint_as_float(b << 16);
}

// Kernel A (MFMA): per-ray min over M points of e = 0.5*dist^2, via
// D[i][j] = -p_i.q_j + 0.5|q_j|^2 + 0.5|p_i|^2  (one 16x16x32 bf16 mfma / tile).
// K-slots: A=[-p.x,-p.y,-p.z, 1, hp_hi, hp_lo, 0,0(+k8..31=0)]
//          B=[ q.x, q.y, q.z, hq,  1,    1,   0,0]  (hq=0.5|q|^2)
// All 64 lanes load the same 16B/point B-frag; A is zero for k>=8 so the
// garbage k-slots in quads 1-3 contribute nothing.
// Grid (N/64, B), block 256 = 4 waves x 16 rays. LDS: M*16B = 64KB.
__global__ __launch_bounds__(256, 2) void chamfer_mfma_kernel(
    const float* __restrict__ cparam,   // B x 25
    const float* __restrict__ depth,    // B x N
    const float* __restrict__ pc,       // B x M x 3
    float* __restrict__ d0,             // B x N (clamped >= 0)
    int N, int M, int R)
{
    const int b    = blockIdx.y;
    const int tid  = threadIdx.x;
    const int lane = tid & 63;
    const int wave = tid >> 6;
    const int m16  = lane & 15;          // row/col within tile
    const int quad = lane >> 4;

    extern __shared__ uint4 sld[];       // M entries of 16B (8 bf16)

    // ---- stage point cloud as pre-packed B-fragments ----
    const float* pcb = pc + (size_t)b * M * 3;
    const int Ms = M >> 8;               // points per thread (16)
    for (int s = 0; s < Ms; s++) {
        const int idx = s * 256 + tid;
        const float x = pcb[idx * 3 + 0];
        const float y = pcb[idx * 3 + 1];
        const float z = pcb[idx * 3 + 2];
        const float hq = 0.5f * (x * x + y * y + z * z);
        uint4 u;
        u.x = f2bf(x) | (f2bf(y) << 16);
        u.y = f2bf(z) | (f2bf(hq) << 16);
        u.z = 0x3F803F80u;               // [1.0, 1.0]
        u.w = 0u;
        sld[idx] = u;
    }
    __syncthreads();

    // ---- camera + per-lane ray (ray = nbase + m16; 4 lanes redundant) ----
    const float* cb = cparam + (size_t)b * 25;
    const float fx = cb[16], sk = cb[17], cx = cb[18];
    const float fy = cb[20], cy = cb[21];

    const int nbase = blockIdx.x * 64 + wave * 16;
    const int n  = nbase + m16;
    const int i0 = n / R;
    const int j0 = n - i0 * R;
    const float x_cam = (j0 + 0.5f) / (float)R;
    const float y_cam = (i0 + 0.5f) / (float)R;
    const float x_lift = (x_cam - cx + cy * sk / fy - sk * y_cam / fy) / fx;
    const float y_lift = (y_cam - cy) / fy;
    const float dxw = cb[0] * x_lift + cb[1] * y_lift + cb[2];
    const float dyw = cb[4] * x_lift + cb[5] * y_lift + cb[6];
    const float dzw = cb[8] * x_lift + cb[9] * y_lift + cb[10];
    const float inv = 1.0f / sqrtf(dxw * dxw + dyw * dyw + dzw * dzw);
    const float dep = depth[(size_t)b * N + n];
    const float px = cb[3]  + dep * dxw * inv;
    const float py = cb[7]  + dep * dyw * inv;
    const float pz = cb[11] + dep * dzw * inv;

    const float hp = 0.5f * (px * px + py * py + pz * pz);
    const unsigned int hp_hi = f2bf(hp);
    const unsigned int hp_lo = f2bf(hp - bf2f(hp_hi));

    U4S8 af;
    af.u = make_uint4(0u, 0u, 0u, 0u);
    if (quad == 0) {
        af.u.x = f2bf(-px) | (f2bf(-py) << 16);
        af.u.y = f2bf(-pz) | (0x3F80u << 16);      // [-pz, 1.0]
        af.u.z = hp_hi | (hp_lo << 16);
        af.u.w = 0u;
    }
    const short8 afrag = af.s;
    const floatx4 zero4 = {0.0f, 0.0f, 0.0f, 0.0f};

    floatx4 mins = {FLT_BIG, FLT_BIG, FLT_BIG, FLT_BIG};

    // ---- main loop: 8 B-frag loads in flight, then 8 mfma + 32 mins ----
    const int T = M >> 4;                // tiles (256)
    for (int m = 0; m < T; m += 8) {
        uint4 bu[8];
        #pragma unroll
        for (int mm = 0; mm < 8; mm++)
            bu[mm] = sld[((m + mm) << 4) + m16];
        #pragma unroll
        for (int mm = 0; mm < 8; mm++) {
            U4S8 bf; bf.u = bu[mm];
            floatx4 d = __builtin_amdgcn_mfma_f32_16x16x32_bf16(
                            afrag, bf.s, zero4, 0, 0, 0);
            mins[0] = fminf(mins[0], d[0]);
            mins[1] = fminf(mins[1], d[1]);
            mins[2] = fminf(mins[2], d[2]);
            mins[3] = fminf(mins[3], d[3]);
        }
    }

    // ---- reduce over cols (16 lanes per quad); rows = quad*4 + reg ----
    float dv[4];
    #pragma unroll
    for (int t = 0; t < 4; t++) {
        float v = mins[t];
        v = fminf(v, __shfl_xor(v, 1));
        v = fminf(v, __shfl_xor(v, 2));
        v = fminf(v, __shfl_xor(v, 4));
        v = fminf(v, __shfl_xor(v, 8));
        dv[t] = fmaxf(2.0f * v, 0.0f);   // dist^2, clamped (uint-monotone bits)
    }
    if (m16 == 0) {
        float4* o = (float4*)(d0 + (size_t)b * N + nbase + quad * 4);
        *o = make_float4(dv[0], dv[1], dv[2], dv[3]);
    }
}

// Kernel B: per-batch histogram select (unchanged from round 8).
__global__ __launch_bounds__(256, 1) void select_mean_kernel(
    const float* __restrict__ d0,
    float* __restrict__ out,
    int N, int K)
{
    const int b   = blockIdx.x;
    const int tid = threadIdx.x;

    extern __shared__ unsigned int hist[];   // HIST_BINS
    __shared__ unsigned int spart[256];
    __shared__ unsigned int s_selbin, s_krem;
    __shared__ unsigned int subcnt[32];
    __shared__ float        subsum[32];
    __shared__ float        s_below;

    for (int t2 = tid; t2 < HIST_BINS; t2 += 256) hist[t2] = 0u;
    if (tid < 32) { subcnt[tid] = 0u; subsum[tid] = 0.0f; }
    if (tid == 0) s_below = 0.0f;
    __syncthreads();

    unsigned int key[16];
    #pragma unroll
    for (int t2 = 0; t2 < 16; t2++)
        key[t2] = __float_as_uint(d0[(size_t)b * N + t2 * 256 + tid]);
    #pragma unroll
    for (int t2 = 0; t2 < 16; t2++)
        atomicAdd(&hist[key[t2] >> 18], 1u);
    __syncthreads();

    unsigned int psum = 0u;
    #pragma unroll 8
    for (int i2 = 0; i2 < 64; i2++)
        psum += hist[(tid << 6) + ((i2 + tid) & 63)];
    spart[tid] = psum;
    __syncthreads();

    unsigned int cbef = 0u;
    for (int i2 = 0; i2 < tid; i2++) cbef += spart[i2];
    if (cbef < (unsigned int)K && (unsigned int)K <= cbef + psum) {
        unsigned int k2 = (unsigned int)K - cbef;
        unsigned int sel = 0u;
        for (int i2 = 0; i2 < 64; i2++) {
            unsigned int h = hist[(tid << 6) + i2];
            if (k2 <= h) { sel = (tid << 6) + i2; break; }
            k2 -= h;
        }
        s_selbin = sel;
        s_krem   = k2;
    }
    __syncthreads();

    const unsigned int selbin = s_selbin;
    float sumb = 0.0f;
    #pragma unroll
    for (int t2 = 0; t2 < 16; t2++) {
        const unsigned int bin = key[t2] >> 18;
        const float v = __uint_as_float(key[t2]);
        if (bin < selbin) sumb += v;
        if (bin == selbin) {
            const unsigned int sub = (key[t2] >> 13) & 31u;
            atomicAdd(&subcnt[sub], 1u);
            atomicAdd(&subsum[sub], v);
        }
    }
    atomicAdd(&s_below, sumb);
    __syncthreads();

    if (tid == 0) {
        unsigned int k2 = s_krem;
        float s = s_below;
        for (int i2 = 0; i2 < 32; i2++) {
            unsigned int h = subcnt[i2];
            if (k2 <= h) {
                s += (h ? (subsum[i2] * ((float)k2 / (float)h)) : 0.0f);
                break;
            }
            s += subsum[i2];
            k2 -= h;
        }
        out[b] = 2.0f * s / (float)K;
    }
}

extern "C" void kernel_launch(void* const* d_in, const int* in_sizes, int n_in,
                              void* d_out, int out_size, void* d_ws, size_t ws_size,
                              hipStream_t stream)
{
    const float* c   = (const float*)d_in[0];
    const float* dep = (const float*)d_in[1];
    const float* pc  = (const float*)d_in[2];
    float* out = (float*)d_out;

    const int B = in_sizes[0] / 25;
    const int N = in_sizes[1] / B;     // 4096 (= 16*256, assumed by kernel B)
    const int M = in_sizes[2] / (3 * B);
    int R = 1; while (R * R < N) R++;

    float* d0 = (float*)d_ws;          // B*N floats of scratch

    dim3 gridA(N / 64, B);
    size_t ldsA = (size_t)M * sizeof(uint4);   // 64KB
    hipLaunchKernelGGL(chamfer_mfma_kernel, gridA, dim3(256), ldsA, stream,
                       c, dep, pc, d0, N, M, R);

    const int K = ((N < M) ? N : M) / 2;
    size_t ldsB = (size_t)HIST_BINS * sizeof(unsigned int);
    hipLaunchKernelGGL(select_mean_kernel, dim3(B), dim3(256), ldsB, stream,
                       d0, out, N, K);
}

// Round 10
// 80.722 us; speedup vs baseline: 1.5919x; 1.0140x over previous
//
#include <hip/hip_runtime.h>
#include <math.h>

#define FLT_BIG 3.0e38f
#define HIST_BINS 16384   // float bits >> 18 : sign(0)+exp(8)+mant(5)

typedef short short8 __attribute__((ext_vector_type(8)));
typedef float floatx4 __attribute__((ext_vector_type(4)));
typedef float floatx16 __attribute__((ext_vector_type(16)));

union U4S8 { uint4 u; short8 s; };

// round-to-nearest-even f32 -> bf16 bits
static __device__ __forceinline__ unsigned int f2bf(float f) {
    unsigned int u = __float_as_uint(f);
    return (u + 0x7FFFu + ((u >> 16) & 1u)) >> 16;
}
static __device__ __forceinline__ float bf2f(unsigned int b) {
    return __uint_as_float(b << 16);
}

// Kernel A (MFMA 32x32x16): D[i][j] = -p_i.q_j + 0.5|q_j|^2 + 0.5|p_i|^2 = 0.5 d^2.
// K-slots (k=0..7, lower half): A=[-p.x,-p.y,-p.z, 1, hp_hi, hp_lo, 0, 0]
//                               B=[ q.x, q.y, q.z, hq,  1,    1,   0, 0]
// A upper lanes (k=8..15) are ZERO, so B upper lanes multiply by zero -> all 64
// lanes read the same 16B point frag (2-way broadcast, conflict-free).
// Block 256 = 4 waves: wave w -> rays (w&1)*32..+32, M-half (w>>1).
// Grid (N/64, B). LDS: M*16B = 64KB -> 2 blocks/CU.
__global__ __launch_bounds__(256, 2) void chamfer_mfma_kernel(
    const float* __restrict__ cparam,   // B x 25
    const float* __restrict__ depth,    // B x N
    const float* __restrict__ pc,       // B x M x 3
    float* __restrict__ d0,             // B x N (clamped >= 0)
    int N, int M, int R)
{
    const int b    = blockIdx.y;
    const int tid  = threadIdx.x;
    const int lane = tid & 63;
    const int wv   = tid >> 6;           // wave 0..3
    const int row  = lane & 31;          // A-row / B-col / D-col
    const int half = lane >> 5;          // k-group: 0 -> k0..7, 1 -> k8..15

    extern __shared__ uint4 sld[];       // M entries of 16B (8 bf16 B-frag)
    __shared__ float smin[4][32];

    // ---- stage point cloud as pre-packed B-fragments (same as 16x16 format) ----
    const float* pcb = pc + (size_t)b * M * 3;
    const int Ms = M >> 8;               // points per thread (16)
    for (int s = 0; s < Ms; s++) {
        const int idx = s * 256 + tid;
        const float x = pcb[idx * 3 + 0];
        const float y = pcb[idx * 3 + 1];
        const float z = pcb[idx * 3 + 2];
        const float hq = 0.5f * (x * x + y * y + z * z);
        uint4 u;
        u.x = f2bf(x) | (f2bf(y) << 16);
        u.y = f2bf(z) | (f2bf(hq) << 16);
        u.z = 0x3F803F80u;               // [1.0, 1.0] multiplies hp_hi, hp_lo
        u.w = 0u;
        sld[idx] = u;
    }
    __syncthreads();

    // ---- camera + per-lane ray ----
    const float* cb = cparam + (size_t)b * 25;
    const float fx = cb[16], sk = cb[17], cx = cb[18];
    const float fy = cb[20], cy = cb[21];

    const int nbase = blockIdx.x * 64;
    const int n  = nbase + (wv & 1) * 32 + row;
    const int i0 = n / R;
    const int j0 = n - i0 * R;
    const float x_cam = (j0 + 0.5f) / (float)R;
    const float y_cam = (i0 + 0.5f) / (float)R;
    const float x_lift = (x_cam - cx + cy * sk / fy - sk * y_cam / fy) / fx;
    const float y_lift = (y_cam - cy) / fy;
    const float dxw = cb[0] * x_lift + cb[1] * y_lift + cb[2];
    const float dyw = cb[4] * x_lift + cb[5] * y_lift + cb[6];
    const float dzw = cb[8] * x_lift + cb[9] * y_lift + cb[10];
    const float inv = 1.0f / sqrtf(dxw * dxw + dyw * dyw + dzw * dzw);
    const float dep = depth[(size_t)b * N + n];
    const float px = cb[3]  + dep * dxw * inv;
    const float py = cb[7]  + dep * dyw * inv;
    const float pz = cb[11] + dep * dzw * inv;

    const float hp = 0.5f * (px * px + py * py + pz * pz);
    const unsigned int hp_hi = f2bf(hp);
    const unsigned int hp_lo = f2bf(hp - bf2f(hp_hi));

    U4S8 af;
    af.u = make_uint4(0u, 0u, 0u, 0u);
    if (half == 0) {                     // k=8..15 (upper lanes) stay zero
        af.u.x = f2bf(-px) | (f2bf(-py) << 16);
        af.u.y = f2bf(-pz) | (0x3F80u << 16);      // [-pz, 1.0]
        af.u.z = hp_hi | (hp_lo << 16);
    }
    const short8 afrag = af.s;
    const floatx16 zero16 = {0,0,0,0,0,0,0,0,0,0,0,0,0,0,0,0};

    float minsA[16], minsB[16];
    #pragma unroll
    for (int t = 0; t < 16; t++) { minsA[t] = FLT_BIG; minsB[t] = FLT_BIG; }

    // ---- main loop: this wave's M-half, 64 B-frags of 32 points ----
    const int fbase = (wv >> 1) * 64;    // frag index base (frag = 32 points)
    for (int f = 0; f < 64; f += 8) {
        uint4 bu[8];
        #pragma unroll
        for (int mm = 0; mm < 8; mm++)
            bu[mm] = sld[((fbase + f + mm) << 5) + row];
        #pragma unroll
        for (int mm = 0; mm < 8; mm++) {
            U4S8 bf; bf.u = bu[mm];
            floatx16 d = __builtin_amdgcn_mfma_f32_32x32x16_bf16(
                             afrag, bf.s, zero16, 0, 0, 0);
            if (mm & 1) {
                #pragma unroll
                for (int t = 0; t < 16; t++) minsB[t] = fminf(minsB[t], d[t]);
            } else {
                #pragma unroll
                for (int t = 0; t < 16; t++) minsA[t] = fminf(minsA[t], d[t]);
            }
        }
    }

    // ---- reduce over the 32 cols (within each 32-lane half) ----
    #pragma unroll
    for (int t = 0; t < 16; t++) {
        float v = fminf(minsA[t], minsB[t]);
        v = fminf(v, __shfl_xor(v, 1));
        v = fminf(v, __shfl_xor(v, 2));
        v = fminf(v, __shfl_xor(v, 4));
        v = fminf(v, __shfl_xor(v, 8));
        v = fminf(v, __shfl_xor(v, 16));
        minsA[t] = v;
    }
    // rows for reg t: (t&3) + 8*(t>>2) + 4*half
    if (row == 0) {
        #pragma unroll
        for (int t = 0; t < 16; t++)
            smin[wv][(t & 3) + 8 * (t >> 2) + 4 * half] = minsA[t];
    }
    __syncthreads();

    // combine M-halves: rays 0-31 in waves {0,2}, rays 32-63 in waves {1,3}
    if (tid < 64) {
        const int g  = tid >> 5;         // 0 or 1
        const int rr = tid & 31;
        const float v = fminf(smin[g][rr], smin[g + 2][rr]);
        d0[(size_t)b * N + nbase + tid] = fmaxf(2.0f * v, 0.0f);
    }
}

// Kernel B: per-batch histogram select (unchanged).
__global__ __launch_bounds__(256, 1) void select_mean_kernel(
    const float* __restrict__ d0,
    float* __restrict__ out,
    int N, int K)
{
    const int b   = blockIdx.x;
    const int tid = threadIdx.x;

    extern __shared__ unsigned int hist[];   // HIST_BINS
    __shared__ unsigned int spart[256];
    __shared__ unsigned int s_selbin, s_krem;
    __shared__ unsigned int subcnt[32];
    __shared__ float        subsum[32];
    __shared__ float        s_below;

    for (int t2 = tid; t2 < HIST_BINS; t2 += 256) hist[t2] = 0u;
    if (tid < 32) { subcnt[tid] = 0u; subsum[tid] = 0.0f; }
    if (tid == 0) s_below = 0.0f;
    __syncthreads();

    unsigned int key[16];
    #pragma unroll
    for (int t2 = 0; t2 < 16; t2++)
        key[t2] = __float_as_uint(d0[(size_t)b * N + t2 * 256 + tid]);
    #pragma unroll
    for (int t2 = 0; t2 < 16; t2++)
        atomicAdd(&hist[key[t2] >> 18], 1u);
    __syncthreads();

    unsigned int psum = 0u;
    #pragma unroll 8
    for (int i2 = 0; i2 < 64; i2++)
        psum += hist[(tid << 6) + ((i2 + tid) & 63)];
    spart[tid] = psum;
    __syncthreads();

    unsigned int cbef = 0u;
    for (int i2 = 0; i2 < tid; i2++) cbef += spart[i2];
    if (cbef < (unsigned int)K && (unsigned int)K <= cbef + psum) {
        unsigned int k2 = (unsigned int)K - cbef;
        unsigned int sel = 0u;
        for (int i2 = 0; i2 < 64; i2++) {
            unsigned int h = hist[(tid << 6) + i2];
            if (k2 <= h) { sel = (tid << 6) + i2; break; }
            k2 -= h;
        }
        s_selbin = sel;
        s_krem   = k2;
    }
    __syncthreads();

    const unsigned int selbin = s_selbin;
    float sumb = 0.0f;
    #pragma unroll
    for (int t2 = 0; t2 < 16; t2++) {
        const unsigned int bin = key[t2] >> 18;
        const float v = __uint_as_float(key[t2]);
        if (bin < selbin) sumb += v;
        if (bin == selbin) {
            const unsigned int sub = (key[t2] >> 13) & 31u;
            atomicAdd(&subcnt[sub], 1u);
            atomicAdd(&subsum[sub], v);
        }
    }
    atomicAdd(&s_below, sumb);
    __syncthreads();

    if (tid == 0) {
        unsigned int k2 = s_krem;
        float s = s_below;
        for (int i2 = 0; i2 < 32; i2++) {
            unsigned int h = subcnt[i2];
            if (k2 <= h) {
                s += (h ? (subsum[i2] * ((float)k2 / (float)h)) : 0.0f);
                break;
            }
            s += subsum[i2];
            k2 -= h;
        }
        out[b] = 2.0f * s / (float)K;
    }
}

extern "C" void kernel_launch(void* const* d_in, const int* in_sizes, int n_in,
                              void* d_out, int out_size, void* d_ws, size_t ws_size,
                              hipStream_t stream)
{
    const float* c   = (const float*)d_in[0];
    const float* dep = (const float*)d_in[1];
    const float* pc  = (const float*)d_in[2];
    float* out = (float*)d_out;

    const int B = in_sizes[0] / 25;
    const int N = in_sizes[1] / B;     // 4096 (= 16*256, assumed by kernel B)
    const int M = in_sizes[2] / (3 * B);
    int R = 1; while (R * R < N) R++;

    float* d0 = (float*)d_ws;          // B*N floats of scratch

    dim3 gridA(N / 64, B);
    size_t ldsA = (size_t)M * sizeof(uint4);   // 64KB
    hipLaunchKernelGGL(chamfer_mfma_kernel, gridA, dim3(256), ldsA, stream,
                       c, dep, pc, d0, N, M, R);

    const int K = ((N < M) ? N : M) / 2;
    size_t ldsB = (size_t)HIST_BINS * sizeof(unsigned int);
    hipLaunchKernelGGL(select_mean_kernel, dim3(B), dim3(256), ldsB, stream,
                       d0, out, N, K);
}